// Round 2
// baseline (450.924 us; speedup 1.0000x reference)
//
#include <hip/hip_runtime.h>

#define OBS 8
#define PREDL 12
#define NSTEP 19   // 8 obs + 11 pred-advance steps

// LDS map (bytes)
#define W_IF_OFF  0        // 65536: W_hh rows 0..255 (gates i,f), 256B rows, swizzled
#define W_EXT_OFF 65536    // 16384: 512 rows x 32B: [Wih0, Wih1, bias, 0...] bf16
#define H_OFF     81920    // 2 x 32768: h double buffer, 128 rows x 256B, swizzled
#define SCR_OFF   147456   // 8192: head partials [parity][wc][row][2] f32
#define RED_OFF   155648   // 64: loss partials
#define LDS_BYTES 155712

typedef short short8 __attribute__((ext_vector_type(8)));
typedef float f32x16 __attribute__((ext_vector_type(16)));
struct U128 { unsigned a, b, c, d; };

__device__ __forceinline__ float sigm(float x) {
    return __builtin_amdgcn_rcpf(1.0f + __builtin_amdgcn_exp2f(x * -1.4426950408889634f));
}
__device__ __forceinline__ float tanh_(float x) {
    return __builtin_amdgcn_rcpf(1.0f + __builtin_amdgcn_exp2f(x * -2.8853900817779268f)) * 2.0f - 1.0f;
}
__device__ __forceinline__ unsigned f2bf(float f) {
    unsigned u = __builtin_bit_cast(unsigned, f);
    u += 0x7fffu + ((u >> 16) & 1u);   // RNE
    return u >> 16;
}
// DPP add: v += dpp(v, ctrl), bound_ctrl=1 (OOB -> 0)
#define DPP_ADD(v, ctrl) \
    v += __builtin_bit_cast(float, __builtin_amdgcn_update_dpp(0, __builtin_bit_cast(int, v), ctrl, 0xf, 0xf, true))

__global__ __launch_bounds__(512, 2)
void lstm_persist(const float* __restrict__ traj_in, const float* __restrict__ traj_gt,
                  const float* __restrict__ W_ih, const float* __restrict__ W_hh,
                  const float* __restrict__ b_ih, const float* __restrict__ b_hh,
                  const float* __restrict__ W_last, const float* __restrict__ b_last,
                  float* __restrict__ out, float* __restrict__ ws)
{
    extern __shared__ char smem[];
    const int tid  = threadIdx.x;
    const int lane = tid & 63;
    const int wave = tid >> 6;
    const int l31  = lane & 31;
    const int half = lane >> 5;
    const int sw   = (lane & 7) << 4;
    const int wm   = wave >> 2;       // M-tile group: rows wm*64..+63
    const int wc   = wave & 3;        // col group: gate cols wc*32..+31 of each gate
    const int col0 = wc * 32;
    const int b0   = blockIdx.x * 128;

    // ---- stage W_hh gates i,f (rows 0..255) -> LDS bf16, swizzled rows
    for (int it = 0; it < 32; ++it) {
        int idx = it * 512 + tid;
        int n = idx >> 6, pr = idx & 63;
        float2 w = *(const float2*)(W_hh + n * 128 + pr * 2);
        unsigned pk = f2bf(w.x) | (f2bf(w.y) << 16);
        *(unsigned*)(smem + W_IF_OFF + n * 256 + ((pr * 4) ^ ((n & 7) << 4))) = pk;
    }
    // ---- stage W_ext: row n = [Wih[n][0], Wih[n][1], b_ih[n]+b_hh[n], 0 x13] bf16
    {
        int n = tid;
        float2 wi = *(const float2*)(W_ih + n * 2);
        float bsum = b_ih[n] + b_hh[n];
        char* p = smem + W_EXT_OFF + n * 32;
        *(unsigned*)(p +  0) = f2bf(wi.x) | (f2bf(wi.y) << 16);
        *(unsigned*)(p +  4) = f2bf(bsum);
        *(unsigned*)(p +  8) = 0u; *(unsigned*)(p + 12) = 0u;
        *(unsigned*)(p + 16) = 0u; *(unsigned*)(p + 20) = 0u;
        *(unsigned*)(p + 24) = 0u; *(unsigned*)(p + 28) = 0u;
    }
    // ---- zero h buffer 0
    for (int i = 0; i < 16; ++i)
        *(unsigned*)(smem + H_OFF + (tid + i * 512) * 4) = 0u;

    // ---- gates g,o B-fragments -> registers (one-time global load)
    short8 Bg[2][8];
    #pragma unroll
    for (int G = 0; G < 2; ++G)
        #pragma unroll
        for (int ks = 0; ks < 8; ++ks) {
            const float* p = W_hh + (size_t)((2 + G) * 128 + col0 + l31) * 128 + ks * 16 + half * 8;
            float4 u = *(const float4*)p;
            float4 v = *(const float4*)(p + 4);
            U128 q = { f2bf(u.x) | (f2bf(u.y) << 16), f2bf(u.z) | (f2bf(u.w) << 16),
                       f2bf(v.x) | (f2bf(v.y) << 16), f2bf(v.z) | (f2bf(v.w) << 16) };
            Bg[G][ks] = __builtin_bit_cast(short8, q);
        }

    const float wl0 = W_last[col0 + l31];
    const float wl1 = W_last[128 + col0 + l31];
    const float bl0 = b_last[0], bl1 = b_last[1];

    __syncthreads();

    float c_[2][16];
    #pragma unroll
    for (int m = 0; m < 2; ++m)
        #pragma unroll
        for (int r = 0; r < 16; ++r) c_[m][r] = 0.f;
    float lossAcc = 0.f;
    unsigned xv0 = 0u, xv1 = 0u;   // packed bf16 (x0,x1) per mtile, valid at half==0

    for (int t = 0; t < NSTEP; ++t) {
        const int hcur = H_OFF + (t & 1) * 32768;
        const int hnxt = H_OFF + ((t & 1) ^ 1) * 32768;
        const bool doHead = (t >= OBS - 1);

        // ---- acquire x for this step
        if (t < OBS) {
            if (half == 0) {
                int r0 = b0 + wm * 64 + l31;
                float2 xa = *(const float2*)(traj_in + ((size_t)r0 * OBS + t) * 2);
                float2 xb = *(const float2*)(traj_in + ((size_t)(r0 + 32) * OBS + t) * 2);
                xv0 = f2bf(xa.x) | (f2bf(xa.y) << 16);
                xv1 = f2bf(xb.x) | (f2bf(xb.y) << 16);
            }
        } else {
            const int sp = (t - 1) & 1;
            if (half == 0) {
                #pragma unroll
                for (int m = 0; m < 2; ++m) {
                    int row = wm * 64 + m * 32 + l31;
                    const char* base = smem + SCR_OFF + (sp * 512 + row) * 8;
                    float2 s0 = *(const float2*)(base);
                    float2 s1 = *(const float2*)(base + 1024);
                    float2 s2 = *(const float2*)(base + 2048);
                    float2 s3 = *(const float2*)(base + 3072);
                    float o0 = ((s0.x + s1.x) + (s2.x + s3.x)) + bl0;
                    float o1 = ((s0.y + s1.y) + (s2.y + s3.y)) + bl1;
                    unsigned pk = f2bf(o0) | (f2bf(o1) << 16);
                    if (m == 0) xv0 = pk; else xv1 = pk;
                    if (wc == 0) {          // emit prediction p = t-8, once per row
                        int p = t - OBS;
                        size_t og = ((size_t)(b0 + row) * PREDL + p) * 2;
                        float2 gt = *(const float2*)(traj_gt + og);
                        *(float2*)(out + og) = make_float2(o0, o1);
                        float d0 = o0 - gt.x, d1 = o1 - gt.y;
                        lossAcc = fmaf(d0, d0, fmaf(d1, d1, lossAcc));
                    }
                }
            }
        }

        #pragma unroll
        for (int m = 0; m < 2; ++m) {
            const int R0 = wm * 64 + m * 32;
            short8 a[8];
            #pragma unroll
            for (int ks = 0; ks < 8; ++ks)
                a[ks] = *(const short8*)(smem + hcur + (R0 + l31) * 256 + ((ks * 32 + half * 16) ^ sw));
            U128 ax = { (half == 0) ? (m == 0 ? xv0 : xv1) : 0u,
                        (half == 0) ? 0x00003F80u : 0u, 0u, 0u };   // [x0,x1],[1.0,0],0,0
            short8 aext = __builtin_bit_cast(short8, ax);

            f32x16 ac0{}, ac1{}, ac2{}, ac3{};
            #pragma unroll
            for (int ks = 0; ks < 8; ++ks) {
                const int bb = (ks * 32 + half * 16) ^ sw;
                short8 bi  = *(const short8*)(smem + W_IF_OFF + (col0 + l31) * 256 + bb);
                short8 bf_ = *(const short8*)(smem + W_IF_OFF + (128 + col0 + l31) * 256 + bb);
                ac0 = __builtin_amdgcn_mfma_f32_32x32x16_bf16(a[ks], bi,        ac0, 0, 0, 0);
                ac1 = __builtin_amdgcn_mfma_f32_32x32x16_bf16(a[ks], bf_,       ac1, 0, 0, 0);
                ac2 = __builtin_amdgcn_mfma_f32_32x32x16_bf16(a[ks], Bg[0][ks], ac2, 0, 0, 0);
                ac3 = __builtin_amdgcn_mfma_f32_32x32x16_bf16(a[ks], Bg[1][ks], ac3, 0, 0, 0);
            }
            {   // K-extension slice: x * W_ih^T + bias
                const int eb = half * 16;
                short8 e0 = *(const short8*)(smem + W_EXT_OFF + (col0 + l31) * 32 + eb);
                short8 e1 = *(const short8*)(smem + W_EXT_OFF + (128 + col0 + l31) * 32 + eb);
                short8 e2 = *(const short8*)(smem + W_EXT_OFF + (256 + col0 + l31) * 32 + eb);
                short8 e3 = *(const short8*)(smem + W_EXT_OFF + (384 + col0 + l31) * 32 + eb);
                ac0 = __builtin_amdgcn_mfma_f32_32x32x16_bf16(aext, e0, ac0, 0, 0, 0);
                ac1 = __builtin_amdgcn_mfma_f32_32x32x16_bf16(aext, e1, ac1, 0, 0, 0);
                ac2 = __builtin_amdgcn_mfma_f32_32x32x16_bf16(aext, e2, ac2, 0, 0, 0);
                ac3 = __builtin_amdgcn_mfma_f32_32x32x16_bf16(aext, e3, ac3, 0, 0, 0);
            }

            #pragma unroll
            for (int r = 0; r < 16; ++r) {
                float iv = sigm(ac0[r]);
                float fv = sigm(ac1[r]);
                float gv = tanh_(ac2[r]);
                float ov = sigm(ac3[r]);
                float cv = fmaf(fv, c_[m][r], iv * gv);
                c_[m][r] = cv;
                float hv = ov * tanh_(cv);
                const int rrow = (r & 3) + 8 * (r >> 2) + 4 * half;  // row within mtile
                const int arow = R0 + rrow;                           // absolute row
                // pair-packed h write (even lanes write b32) via DPP quad_perm swap
                unsigned ubf = f2bf(hv);
                unsigned nb  = (unsigned)__builtin_amdgcn_update_dpp(0, (int)ubf, 0xB1, 0xf, 0xf, true);
                if (!(l31 & 1))
                    *(unsigned*)(smem + hnxt + arow * 256 +
                                 (((col0 + l31) * 2) ^ ((rrow & 7) << 4))) = ubf | (nb << 16);
                if (doHead) {
                    float rl = fmaxf(hv, 0.f);
                    float v0 = rl * wl0, v1 = rl * wl1;
                    // 32-lane sum into lanes 31/63 via DPP row_shr + row_bcast15
                    DPP_ADD(v0, 0x111); DPP_ADD(v0, 0x112); DPP_ADD(v0, 0x114);
                    DPP_ADD(v0, 0x118); DPP_ADD(v0, 0x142);
                    DPP_ADD(v1, 0x111); DPP_ADD(v1, 0x112); DPP_ADD(v1, 0x114);
                    DPP_ADD(v1, 0x118); DPP_ADD(v1, 0x142);
                    if (l31 == 31)
                        *(float2*)(smem + SCR_OFF + (((t & 1) * 4 + wc) * 128 + arow) * 8) =
                            make_float2(v0, v1);
                }
            }
        }
        __syncthreads();
    }

    // ---- tail: emit p = 11 from head(18) partials (parity (NSTEP-1)&1 == 0)
    if (half == 0 && wc == 0) {
        #pragma unroll
        for (int m = 0; m < 2; ++m) {
            int row = wm * 64 + m * 32 + l31;
            const char* base = smem + SCR_OFF + row * 8;
            float2 s0 = *(const float2*)(base);
            float2 s1 = *(const float2*)(base + 1024);
            float2 s2 = *(const float2*)(base + 2048);
            float2 s3 = *(const float2*)(base + 3072);
            float o0 = ((s0.x + s1.x) + (s2.x + s3.x)) + bl0;
            float o1 = ((s0.y + s1.y) + (s2.y + s3.y)) + bl1;
            size_t og = ((size_t)(b0 + row) * PREDL + (PREDL - 1)) * 2;
            float2 gt = *(const float2*)(traj_gt + og);
            *(float2*)(out + og) = make_float2(o0, o1);
            float d0 = o0 - gt.x, d1 = o1 - gt.y;
            lossAcc = fmaf(d0, d0, fmaf(d1, d1, lossAcc));
        }
    }

    // ---- block loss partial (deterministic)
    #pragma unroll
    for (int s = 1; s < 64; s <<= 1) lossAcc += __shfl_xor(lossAcc, s, 64);
    float* sred = (float*)(smem + RED_OFF);
    if (lane == 0) sred[wave] = lossAcc;
    __syncthreads();
    if (tid == 0) {
        float s = 0.f;
        #pragma unroll
        for (int i = 0; i < 8; ++i) s += sred[i];
        ws[blockIdx.x] = s;
    }
}

__global__ void loss_reduce(const float* __restrict__ ws, float* __restrict__ out,
                            int nblk, int nelem)
{
    __shared__ float sacc[4];
    int tid = threadIdx.x;
    float v = (tid < nblk) ? ws[tid] : 0.f;
    #pragma unroll
    for (int s = 1; s < 64; s <<= 1) v += __shfl_xor(v, s, 64);
    if ((tid & 63) == 0) sacc[tid >> 6] = v;
    __syncthreads();
    if (tid == 0) out[nelem] = (sacc[0] + sacc[1] + sacc[2] + sacc[3]) / (float)nelem;
}

extern "C" void kernel_launch(void* const* d_in, const int* in_sizes, int n_in,
                              void* d_out, int out_size, void* d_ws, size_t ws_size,
                              hipStream_t stream)
{
    const float* traj_in = (const float*)d_in[0];
    const float* traj_gt = (const float*)d_in[1];
    const float* W_ih    = (const float*)d_in[2];
    const float* W_hh    = (const float*)d_in[3];
    const float* b_ih    = (const float*)d_in[4];
    const float* b_hh    = (const float*)d_in[5];
    const float* W_last  = (const float*)d_in[6];
    const float* b_last  = (const float*)d_in[7];
    float* out = (float*)d_out;
    float* ws  = (float*)d_ws;

    const int B      = in_sizes[0] / (OBS * 2);   // 32768
    const int blocks = B / 128;                    // 256

    lstm_persist<<<blocks, 512, LDS_BYTES, stream>>>(traj_in, traj_gt, W_ih, W_hh,
                                                     b_ih, b_hh, W_last, b_last, out, ws);
    loss_reduce<<<1, 256, 0, stream>>>(ws, out, blocks, out_size - 1);
}

// Round 3
// 449.186 us; speedup vs baseline: 1.0039x; 1.0039x over previous
//
#include <hip/hip_runtime.h>

#define OBS 8
#define PREDL 12
#define NSTEP 19   // 8 obs + 11 pred-advance steps

// LDS map (bytes)
#define W_IF_OFF  0        // 65536: W_hh rows 0..255 (gates i,f), 256B rows, swizzled
#define H_OFF     65536    // 2 x 32768: h double buffer, 128 rows x 256B, swizzled
#define SCR_OFF   131072   // 8192: head partials [parity][wc][row][2] f32
#define RED_OFF   139264   // 64: loss partials
#define LDS_BYTES 139328

typedef short short8 __attribute__((ext_vector_type(8)));
typedef float f32x16 __attribute__((ext_vector_type(16)));
struct U128 { unsigned a, b, c, d; };

__device__ __forceinline__ float sigm(float x) {
    return __builtin_amdgcn_rcpf(1.0f + __builtin_amdgcn_exp2f(x * -1.4426950408889634f));
}
__device__ __forceinline__ float tanh_(float x) {
    return __builtin_amdgcn_rcpf(1.0f + __builtin_amdgcn_exp2f(x * -2.8853900817779268f)) * 2.0f - 1.0f;
}
__device__ __forceinline__ unsigned f2bf(float f) {
    unsigned u = __builtin_bit_cast(unsigned, f);
    u += 0x7fffu + ((u >> 16) & 1u);   // RNE
    return u >> 16;
}
// DPP add: v += dpp(v, ctrl), bound_ctrl=1 (OOB -> 0)
#define DPP_ADD(v, ctrl) \
    v += __builtin_bit_cast(float, __builtin_amdgcn_update_dpp(0, __builtin_bit_cast(int, v), ctrl, 0xf, 0xf, true))

__global__ __launch_bounds__(512, 1)
void lstm_persist(const float* __restrict__ traj_in, const float* __restrict__ traj_gt,
                  const float* __restrict__ W_ih, const float* __restrict__ W_hh,
                  const float* __restrict__ b_ih, const float* __restrict__ b_hh,
                  const float* __restrict__ W_last, const float* __restrict__ b_last,
                  float* __restrict__ out, float* __restrict__ ws)
{
    extern __shared__ char smem[];
    const int tid  = threadIdx.x;
    const int lane = tid & 63;
    const int wave = tid >> 6;
    const int l31  = lane & 31;
    const int half = lane >> 5;
    const int sw   = (lane & 7) << 4;
    const int wm   = wave >> 2;       // M-tile group: rows wm*64..+63
    const int wc   = wave & 3;        // col group: gate cols wc*32..+31 of each gate
    const int col0 = wc * 32;
    const int b0   = blockIdx.x * 128;

    // ---- stage W_hh gates i,f (rows 0..255) -> LDS bf16, swizzled rows
    for (int it = 0; it < 32; ++it) {
        int idx = it * 512 + tid;
        int n = idx >> 6, pr = idx & 63;
        float2 w = *(const float2*)(W_hh + n * 128 + pr * 2);
        unsigned pk = f2bf(w.x) | (f2bf(w.y) << 16);
        *(unsigned*)(smem + W_IF_OFF + n * 256 + ((pr * 4) ^ ((n & 7) << 4))) = pk;
    }
    // ---- zero h buffer 0
    for (int i = 0; i < 16; ++i)
        *(unsigned*)(smem + H_OFF + (tid + i * 512) * 4) = 0u;

    // ---- gates g,o B-fragments -> registers (one-time global load)
    short8 Bg[2][8];
    #pragma unroll
    for (int G = 0; G < 2; ++G)
        #pragma unroll
        for (int ks = 0; ks < 8; ++ks) {
            const float* p = W_hh + (size_t)((2 + G) * 128 + col0 + l31) * 128 + ks * 16 + half * 8;
            float4 u = *(const float4*)p;
            float4 v = *(const float4*)(p + 4);
            U128 q = { f2bf(u.x) | (f2bf(u.y) << 16), f2bf(u.z) | (f2bf(u.w) << 16),
                       f2bf(v.x) | (f2bf(v.y) << 16), f2bf(v.z) | (f2bf(v.w) << 16) };
            Bg[G][ks] = __builtin_bit_cast(short8, q);
        }
    // ---- K-extension B-fragments (x-weights + bias) -> registers, step-invariant.
    // ext row n (bf16[16]) = [Wih[n][0], Wih[n][1], bias_n, 0 x13]; lane holds elems half*8..+8
    short8 Ee[4];
    #pragma unroll
    for (int gg = 0; gg < 4; ++gg) {
        U128 q = { 0u, 0u, 0u, 0u };
        if (half == 0) {
            int n = gg * 128 + col0 + l31;
            float2 wi = *(const float2*)(W_ih + n * 2);
            float bsum = b_ih[n] + b_hh[n];
            q.a = f2bf(wi.x) | (f2bf(wi.y) << 16);
            q.b = f2bf(bsum);
        }
        Ee[gg] = __builtin_bit_cast(short8, q);
    }

    const float wl0 = W_last[col0 + l31];
    const float wl1 = W_last[128 + col0 + l31];
    const float bl0 = b_last[0], bl1 = b_last[1];

    __syncthreads();

    float c_[2][16];
    #pragma unroll
    for (int m = 0; m < 2; ++m)
        #pragma unroll
        for (int r = 0; r < 16; ++r) c_[m][r] = 0.f;
    float lossAcc = 0.f;
    unsigned xv0 = 0u, xv1 = 0u;   // packed bf16 (x0,x1) per mtile, valid at half==0

    for (int t = 0; t < NSTEP; ++t) {
        const int hcur = H_OFF + (t & 1) * 32768;
        const int hnxt = H_OFF + ((t & 1) ^ 1) * 32768;
        const bool doHead = (t >= OBS - 1);

        // ---- acquire x for this step
        if (t < OBS) {
            if (half == 0) {
                int r0 = b0 + wm * 64 + l31;
                float2 xa = *(const float2*)(traj_in + ((size_t)r0 * OBS + t) * 2);
                float2 xb = *(const float2*)(traj_in + ((size_t)(r0 + 32) * OBS + t) * 2);
                xv0 = f2bf(xa.x) | (f2bf(xa.y) << 16);
                xv1 = f2bf(xb.x) | (f2bf(xb.y) << 16);
            }
        } else {
            const int sp = (t - 1) & 1;
            if (half == 0) {
                #pragma unroll
                for (int m = 0; m < 2; ++m) {
                    int row = wm * 64 + m * 32 + l31;
                    const char* base = smem + SCR_OFF + (sp * 512 + row) * 8;
                    float2 s0 = *(const float2*)(base);
                    float2 s1 = *(const float2*)(base + 1024);
                    float2 s2 = *(const float2*)(base + 2048);
                    float2 s3 = *(const float2*)(base + 3072);
                    float o0 = ((s0.x + s1.x) + (s2.x + s3.x)) + bl0;
                    float o1 = ((s0.y + s1.y) + (s2.y + s3.y)) + bl1;
                    unsigned pk = f2bf(o0) | (f2bf(o1) << 16);
                    if (m == 0) xv0 = pk; else xv1 = pk;
                    if (wc == 0) {          // emit prediction p = t-8, once per row
                        int p = t - OBS;
                        size_t og = ((size_t)(b0 + row) * PREDL + p) * 2;
                        float2 gt = *(const float2*)(traj_gt + og);
                        *(float2*)(out + og) = make_float2(o0, o1);
                        float d0 = o0 - gt.x, d1 = o1 - gt.y;
                        lossAcc = fmaf(d0, d0, fmaf(d1, d1, lossAcc));
                    }
                }
            }
        }

        #pragma unroll
        for (int m = 0; m < 2; ++m) {
            const int R0 = wm * 64 + m * 32;
            short8 a[8];
            #pragma unroll
            for (int ks = 0; ks < 8; ++ks)
                a[ks] = *(const short8*)(smem + hcur + (R0 + l31) * 256 + ((ks * 32 + half * 16) ^ sw));
            U128 ax = { (half == 0) ? (m == 0 ? xv0 : xv1) : 0u,
                        (half == 0) ? 0x00003F80u : 0u, 0u, 0u };   // [x0,x1],[1.0,0],0,0
            short8 aext = __builtin_bit_cast(short8, ax);

            f32x16 ac0{}, ac1{}, ac2{}, ac3{};
            #pragma unroll
            for (int ks = 0; ks < 8; ++ks) {
                const int bb = (ks * 32 + half * 16) ^ sw;
                short8 bi  = *(const short8*)(smem + W_IF_OFF + (col0 + l31) * 256 + bb);
                short8 bf_ = *(const short8*)(smem + W_IF_OFF + (128 + col0 + l31) * 256 + bb);
                ac0 = __builtin_amdgcn_mfma_f32_32x32x16_bf16(a[ks], bi,        ac0, 0, 0, 0);
                ac1 = __builtin_amdgcn_mfma_f32_32x32x16_bf16(a[ks], bf_,       ac1, 0, 0, 0);
                ac2 = __builtin_amdgcn_mfma_f32_32x32x16_bf16(a[ks], Bg[0][ks], ac2, 0, 0, 0);
                ac3 = __builtin_amdgcn_mfma_f32_32x32x16_bf16(a[ks], Bg[1][ks], ac3, 0, 0, 0);
            }
            // K-extension slice: x * W_ih^T + bias (register B-fragments)
            ac0 = __builtin_amdgcn_mfma_f32_32x32x16_bf16(aext, Ee[0], ac0, 0, 0, 0);
            ac1 = __builtin_amdgcn_mfma_f32_32x32x16_bf16(aext, Ee[1], ac1, 0, 0, 0);
            ac2 = __builtin_amdgcn_mfma_f32_32x32x16_bf16(aext, Ee[2], ac2, 0, 0, 0);
            ac3 = __builtin_amdgcn_mfma_f32_32x32x16_bf16(aext, Ee[3], ac3, 0, 0, 0);

            #pragma unroll
            for (int r = 0; r < 16; ++r) {
                float iv = sigm(ac0[r]);
                float fv = sigm(ac1[r]);
                float gv = tanh_(ac2[r]);
                float ov = sigm(ac3[r]);
                float cv = fmaf(fv, c_[m][r], iv * gv);
                c_[m][r] = cv;
                float hv = ov * tanh_(cv);
                const int rrow = (r & 3) + 8 * (r >> 2) + 4 * half;  // row within mtile
                const int arow = R0 + rrow;                           // absolute row
                // pair-packed h write (even lanes write b32) via DPP quad_perm swap
                unsigned ubf = f2bf(hv);
                unsigned nb  = (unsigned)__builtin_amdgcn_update_dpp(0, (int)ubf, 0xB1, 0xf, 0xf, true);
                if (!(l31 & 1))
                    *(unsigned*)(smem + hnxt + arow * 256 +
                                 (((col0 + l31) * 2) ^ ((rrow & 7) << 4))) = ubf | (nb << 16);
                if (doHead) {
                    float rl = fmaxf(hv, 0.f);
                    float v0 = rl * wl0, v1 = rl * wl1;
                    // 32-lane sum into lanes 31/63 via DPP row_shr + row_bcast15
                    DPP_ADD(v0, 0x111); DPP_ADD(v0, 0x112); DPP_ADD(v0, 0x114);
                    DPP_ADD(v0, 0x118); DPP_ADD(v0, 0x142);
                    DPP_ADD(v1, 0x111); DPP_ADD(v1, 0x112); DPP_ADD(v1, 0x114);
                    DPP_ADD(v1, 0x118); DPP_ADD(v1, 0x142);
                    if (l31 == 31)
                        *(float2*)(smem + SCR_OFF + (((t & 1) * 4 + wc) * 128 + arow) * 8) =
                            make_float2(v0, v1);
                }
            }
        }
        __syncthreads();
    }

    // ---- tail: emit p = 11 from head(18) partials (parity (NSTEP-1)&1 == 0)
    if (half == 0 && wc == 0) {
        #pragma unroll
        for (int m = 0; m < 2; ++m) {
            int row = wm * 64 + m * 32 + l31;
            const char* base = smem + SCR_OFF + row * 8;
            float2 s0 = *(const float2*)(base);
            float2 s1 = *(const float2*)(base + 1024);
            float2 s2 = *(const float2*)(base + 2048);
            float2 s3 = *(const float2*)(base + 3072);
            float o0 = ((s0.x + s1.x) + (s2.x + s3.x)) + bl0;
            float o1 = ((s0.y + s1.y) + (s2.y + s3.y)) + bl1;
            size_t og = ((size_t)(b0 + row) * PREDL + (PREDL - 1)) * 2;
            float2 gt = *(const float2*)(traj_gt + og);
            *(float2*)(out + og) = make_float2(o0, o1);
            float d0 = o0 - gt.x, d1 = o1 - gt.y;
            lossAcc = fmaf(d0, d0, fmaf(d1, d1, lossAcc));
        }
    }

    // ---- block loss partial (deterministic)
    #pragma unroll
    for (int s = 1; s < 64; s <<= 1) lossAcc += __shfl_xor(lossAcc, s, 64);
    float* sred = (float*)(smem + RED_OFF);
    if (lane == 0) sred[wave] = lossAcc;
    __syncthreads();
    if (tid == 0) {
        float s = 0.f;
        #pragma unroll
        for (int i = 0; i < 8; ++i) s += sred[i];
        ws[blockIdx.x] = s;
    }
}

__global__ void loss_reduce(const float* __restrict__ ws, float* __restrict__ out,
                            int nblk, int nelem)
{
    __shared__ float sacc[4];
    int tid = threadIdx.x;
    float v = (tid < nblk) ? ws[tid] : 0.f;
    #pragma unroll
    for (int s = 1; s < 64; s <<= 1) v += __shfl_xor(v, s, 64);
    if ((tid & 63) == 0) sacc[tid >> 6] = v;
    __syncthreads();
    if (tid == 0) out[nelem] = (sacc[0] + sacc[1] + sacc[2] + sacc[3]) / (float)nelem;
}

extern "C" void kernel_launch(void* const* d_in, const int* in_sizes, int n_in,
                              void* d_out, int out_size, void* d_ws, size_t ws_size,
                              hipStream_t stream)
{
    const float* traj_in = (const float*)d_in[0];
    const float* traj_gt = (const float*)d_in[1];
    const float* W_ih    = (const float*)d_in[2];
    const float* W_hh    = (const float*)d_in[3];
    const float* b_ih    = (const float*)d_in[4];
    const float* b_hh    = (const float*)d_in[5];
    const float* W_last  = (const float*)d_in[6];
    const float* b_last  = (const float*)d_in[7];
    float* out = (float*)d_out;
    float* ws  = (float*)d_ws;

    const int B      = in_sizes[0] / (OBS * 2);   // 32768
    const int blocks = B / 128;                    // 256

    lstm_persist<<<blocks, 512, LDS_BYTES, stream>>>(traj_in, traj_gt, W_ih, W_hh,
                                                     b_ih, b_hh, W_last, b_last, out, ws);
    loss_reduce<<<1, 256, 0, stream>>>(ws, out, blocks, out_size - 1);
}

// Round 4
// 447.665 us; speedup vs baseline: 1.0073x; 1.0034x over previous
//
#include <hip/hip_runtime.h>

#define OBS 8
#define PREDL 12
#define NSTEP 19   // 8 obs + 11 pred-advance steps

// LDS map (bytes)
#define W_IF_OFF  0        // 65536: W_hh rows 0..255 (gates i,f), 256B rows, swizzled
#define H_OFF     65536    // 2 x 32768: h double buffer, 128 rows x 256B, swizzled
#define SCR_OFF   131072   // 8192: head partials [parity][wc][row][2] f32
#define RED_OFF   139264   // 64: loss partials
#define LDS_BYTES 139328

typedef short short8 __attribute__((ext_vector_type(8)));
typedef float f32x16 __attribute__((ext_vector_type(16)));
struct U128 { unsigned a, b, c, d; };

__device__ __forceinline__ float sigm(float x) {
    return __builtin_amdgcn_rcpf(1.0f + __builtin_amdgcn_exp2f(x * -1.4426950408889634f));
}
__device__ __forceinline__ float tanh_(float x) {
    return __builtin_amdgcn_rcpf(1.0f + __builtin_amdgcn_exp2f(x * -2.8853900817779268f)) * 2.0f - 1.0f;
}
__device__ __forceinline__ unsigned f2bf(float f) {
    unsigned u = __builtin_bit_cast(unsigned, f);
    u += 0x7fffu + ((u >> 16) & 1u);   // RNE
    return u >> 16;
}
#define DPP_ADD(v, ctrl) \
    v += __builtin_bit_cast(float, __builtin_amdgcn_update_dpp(0, __builtin_bit_cast(int, v), ctrl, 0xf, 0xf, true))

// ---- prep: convert W_hh gates g,o (rows 256..511) f32 -> bf16 fragment layout in ws.
// layout: byte ((G*8+ks)*128 + r)*32 + half*16  holds k-elems (ks*16+half*8 .. +8) of gate row r
__global__ void prep_w(const float* __restrict__ W_hh, char* __restrict__ wsb)
{
    int idx = blockIdx.x * 256 + threadIdx.x;   // 4096 items
    int G = idx >> 11, ks = (idx >> 8) & 7, r = (idx >> 1) & 127, hf = idx & 1;
    const float* src = W_hh + (size_t)(256 + G * 128 + r) * 128 + ks * 16 + hf * 8;
    float4 u = *(const float4*)src;
    float4 v = *(const float4*)(src + 4);
    U128 q = { f2bf(u.x) | (f2bf(u.y) << 16), f2bf(u.z) | (f2bf(u.w) << 16),
               f2bf(v.x) | (f2bf(v.y) << 16), f2bf(v.z) | (f2bf(v.w) << 16) };
    *(U128*)(wsb + (size_t)((G * 8 + ks) * 128 + r) * 32 + hf * 16) = q;
}

__global__ __launch_bounds__(512)
void lstm_persist(const float* __restrict__ traj_in, const float* __restrict__ traj_gt,
                  const float* __restrict__ W_ih, const float* __restrict__ W_hh,
                  const float* __restrict__ b_ih, const float* __restrict__ b_hh,
                  const float* __restrict__ W_last, const float* __restrict__ b_last,
                  float* __restrict__ out, const char* __restrict__ wsb,
                  float* __restrict__ wsloss)
{
    extern __shared__ char smem[];
    const int tid  = threadIdx.x;
    const int lane = tid & 63;
    const int wave = tid >> 6;
    const int l31  = lane & 31;
    const int half = lane >> 5;
    const int sw   = (lane & 7) << 4;
    const int wm   = wave >> 2;       // M-tile group: rows wm*64..+63
    const int wc   = wave & 3;        // col group: gate cols wc*32..+31 of each gate
    const int col0 = wc * 32;
    const int b0   = blockIdx.x * 128;

    // ---- stage W_hh gates i,f (rows 0..255) -> LDS bf16, swizzled rows
    for (int it = 0; it < 32; ++it) {
        int idx = it * 512 + tid;
        int n = idx >> 6, pr = idx & 63;
        float2 w = *(const float2*)(W_hh + n * 128 + pr * 2);
        unsigned pk = f2bf(w.x) | (f2bf(w.y) << 16);
        *(unsigned*)(smem + W_IF_OFF + n * 256 + ((pr * 4) ^ ((n & 7) << 4))) = pk;
    }
    // ---- zero h buffer 0
    for (int i = 0; i < 16; ++i)
        *(unsigned*)(smem + H_OFF + (tid + i * 512) * 4) = 0u;

    // ---- K-extension B-fragments (x-weights + bias), step-invariant, 16 VGPRs
    short8 Ee[4];
    #pragma unroll
    for (int gg = 0; gg < 4; ++gg) {
        U128 q = { 0u, 0u, 0u, 0u };
        if (half == 0) {
            int n = gg * 128 + col0 + l31;
            float2 wi = *(const float2*)(W_ih + n * 2);
            float bsum = b_ih[n] + b_hh[n];
            q.a = f2bf(wi.x) | (f2bf(wi.y) << 16);
            q.b = f2bf(bsum);
        }
        Ee[gg] = __builtin_bit_cast(short8, q);
    }

    const float wl0 = W_last[col0 + l31];
    const float wl1 = W_last[128 + col0 + l31];
    const float bl0 = b_last[0], bl1 = b_last[1];

    __syncthreads();

    float c_[2][16];
    #pragma unroll
    for (int m = 0; m < 2; ++m)
        #pragma unroll
        for (int r = 0; r < 16; ++r) c_[m][r] = 0.f;
    float lossAcc = 0.f;
    unsigned xv0 = 0u, xv1 = 0u;   // packed bf16 (x0,x1) per mtile, valid at half==0

    for (int t = 0; t < NSTEP; ++t) {
        const int hcur = H_OFF + (t & 1) * 32768;
        const int hnxt = H_OFF + ((t & 1) ^ 1) * 32768;
        const bool doHead = (t >= OBS - 1);

        // ---- acquire x for this step
        if (t < OBS) {
            if (half == 0) {
                int r0 = b0 + wm * 64 + l31;
                float2 xa = *(const float2*)(traj_in + ((size_t)r0 * OBS + t) * 2);
                float2 xb = *(const float2*)(traj_in + ((size_t)(r0 + 32) * OBS + t) * 2);
                xv0 = f2bf(xa.x) | (f2bf(xa.y) << 16);
                xv1 = f2bf(xb.x) | (f2bf(xb.y) << 16);
            }
        } else {
            const int sp = (t - 1) & 1;
            if (half == 0) {
                #pragma unroll
                for (int m = 0; m < 2; ++m) {
                    int row = wm * 64 + m * 32 + l31;
                    const char* base = smem + SCR_OFF + (sp * 512 + row) * 8;
                    float2 s0 = *(const float2*)(base);
                    float2 s1 = *(const float2*)(base + 1024);
                    float2 s2 = *(const float2*)(base + 2048);
                    float2 s3 = *(const float2*)(base + 3072);
                    float o0 = ((s0.x + s1.x) + (s2.x + s3.x)) + bl0;
                    float o1 = ((s0.y + s1.y) + (s2.y + s3.y)) + bl1;
                    unsigned pk = f2bf(o0) | (f2bf(o1) << 16);
                    if (m == 0) xv0 = pk; else xv1 = pk;
                    if (wc == 0) {          // emit prediction p = t-8, once per row
                        int p = t - OBS;
                        size_t og = ((size_t)(b0 + row) * PREDL + p) * 2;
                        float2 gt = *(const float2*)(traj_gt + og);
                        *(float2*)(out + og) = make_float2(o0, o1);
                        float d0 = o0 - gt.x, d1 = o1 - gt.y;
                        lossAcc = fmaf(d0, d0, fmaf(d1, d1, lossAcc));
                    }
                }
            }
        }

        // ---- accumulate gates: i,f from LDS; g,o streamed from L2-hot ws
        f32x16 acc[2][4] = {};
        #pragma unroll
        for (int ks = 0; ks < 8; ++ks) {
            const int bb = (ks * 32 + half * 16) ^ sw;
            short8 bi  = *(const short8*)(smem + W_IF_OFF + (col0 + l31) * 256 + bb);
            short8 bf_ = *(const short8*)(smem + W_IF_OFF + (128 + col0 + l31) * 256 + bb);
            const char* gb = wsb + (size_t)(ks * 128 + col0 + l31) * 32 + half * 16;
            short8 bg = *(const short8*)(gb);
            short8 bo = *(const short8*)(gb + 32768);
            #pragma unroll
            for (int m = 0; m < 2; ++m) {
                short8 a = *(const short8*)(smem + hcur + (wm * 64 + m * 32 + l31) * 256 + bb);
                acc[m][0] = __builtin_amdgcn_mfma_f32_32x32x16_bf16(a, bi,  acc[m][0], 0, 0, 0);
                acc[m][1] = __builtin_amdgcn_mfma_f32_32x32x16_bf16(a, bf_, acc[m][1], 0, 0, 0);
                acc[m][2] = __builtin_amdgcn_mfma_f32_32x32x16_bf16(a, bg,  acc[m][2], 0, 0, 0);
                acc[m][3] = __builtin_amdgcn_mfma_f32_32x32x16_bf16(a, bo,  acc[m][3], 0, 0, 0);
            }
        }
        // K-extension slice: x * W_ih^T + bias
        #pragma unroll
        for (int m = 0; m < 2; ++m) {
            U128 ax = { (half == 0) ? (m == 0 ? xv0 : xv1) : 0u,
                        (half == 0) ? 0x00003F80u : 0u, 0u, 0u };   // [x0,x1],[1.0,0]
            short8 aext = __builtin_bit_cast(short8, ax);
            acc[m][0] = __builtin_amdgcn_mfma_f32_32x32x16_bf16(aext, Ee[0], acc[m][0], 0, 0, 0);
            acc[m][1] = __builtin_amdgcn_mfma_f32_32x32x16_bf16(aext, Ee[1], acc[m][1], 0, 0, 0);
            acc[m][2] = __builtin_amdgcn_mfma_f32_32x32x16_bf16(aext, Ee[2], acc[m][2], 0, 0, 0);
            acc[m][3] = __builtin_amdgcn_mfma_f32_32x32x16_bf16(aext, Ee[3], acc[m][3], 0, 0, 0);
        }

        // ---- elementwise + h write + head partials
        #pragma unroll
        for (int m = 0; m < 2; ++m) {
            const int R0 = wm * 64 + m * 32;
            float hn0 = 0.f, hn1 = 0.f; (void)hn0; (void)hn1;
            #pragma unroll
            for (int r = 0; r < 16; ++r) {
                float iv = sigm(acc[m][0][r]);
                float fv = sigm(acc[m][1][r]);
                float gv = tanh_(acc[m][2][r]);
                float ov = sigm(acc[m][3][r]);
                float cv = fmaf(fv, c_[m][r], iv * gv);
                c_[m][r] = cv;
                float hv = ov * tanh_(cv);
                const int rrow = (r & 3) + 8 * (r >> 2) + 4 * half;
                const int arow = R0 + rrow;
                unsigned ubf = f2bf(hv);
                unsigned nb  = (unsigned)__builtin_amdgcn_update_dpp(0, (int)ubf, 0xB1, 0xf, 0xf, true);
                if (!(l31 & 1))
                    *(unsigned*)(smem + hnxt + arow * 256 +
                                 (((col0 + l31) * 2) ^ ((rrow & 7) << 4))) = ubf | (nb << 16);
                if (doHead) {
                    float rl = fmaxf(hv, 0.f);
                    float v0 = rl * wl0, v1 = rl * wl1;
                    DPP_ADD(v0, 0x111); DPP_ADD(v0, 0x112); DPP_ADD(v0, 0x114);
                    DPP_ADD(v0, 0x118); DPP_ADD(v0, 0x142);
                    DPP_ADD(v1, 0x111); DPP_ADD(v1, 0x112); DPP_ADD(v1, 0x114);
                    DPP_ADD(v1, 0x118); DPP_ADD(v1, 0x142);
                    if (l31 == 31)
                        *(float2*)(smem + SCR_OFF + (((t & 1) * 4 + wc) * 128 + arow) * 8) =
                            make_float2(v0, v1);
                }
            }
        }
        __syncthreads();
    }

    // ---- tail: emit p = 11 from head(18) partials (parity 0)
    if (half == 0 && wc == 0) {
        #pragma unroll
        for (int m = 0; m < 2; ++m) {
            int row = wm * 64 + m * 32 + l31;
            const char* base = smem + SCR_OFF + row * 8;
            float2 s0 = *(const float2*)(base);
            float2 s1 = *(const float2*)(base + 1024);
            float2 s2 = *(const float2*)(base + 2048);
            float2 s3 = *(const float2*)(base + 3072);
            float o0 = ((s0.x + s1.x) + (s2.x + s3.x)) + bl0;
            float o1 = ((s0.y + s1.y) + (s2.y + s3.y)) + bl1;
            size_t og = ((size_t)(b0 + row) * PREDL + (PREDL - 1)) * 2;
            float2 gt = *(const float2*)(traj_gt + og);
            *(float2*)(out + og) = make_float2(o0, o1);
            float d0 = o0 - gt.x, d1 = o1 - gt.y;
            lossAcc = fmaf(d0, d0, fmaf(d1, d1, lossAcc));
        }
    }

    // ---- block loss partial (deterministic)
    #pragma unroll
    for (int s = 1; s < 64; s <<= 1) lossAcc += __shfl_xor(lossAcc, s, 64);
    float* sred = (float*)(smem + RED_OFF);
    if (lane == 0) sred[wave] = lossAcc;
    __syncthreads();
    if (tid == 0) {
        float s = 0.f;
        #pragma unroll
        for (int i = 0; i < 8; ++i) s += sred[i];
        wsloss[blockIdx.x] = s;
    }
}

__global__ void loss_reduce(const float* __restrict__ wsloss, float* __restrict__ out,
                            int nblk, int nelem)
{
    __shared__ float sacc[4];
    int tid = threadIdx.x;
    float v = (tid < nblk) ? wsloss[tid] : 0.f;
    #pragma unroll
    for (int s = 1; s < 64; s <<= 1) v += __shfl_xor(v, s, 64);
    if ((tid & 63) == 0) sacc[tid >> 6] = v;
    __syncthreads();
    if (tid == 0) out[nelem] = (sacc[0] + sacc[1] + sacc[2] + sacc[3]) / (float)nelem;
}

extern "C" void kernel_launch(void* const* d_in, const int* in_sizes, int n_in,
                              void* d_out, int out_size, void* d_ws, size_t ws_size,
                              hipStream_t stream)
{
    const float* traj_in = (const float*)d_in[0];
    const float* traj_gt = (const float*)d_in[1];
    const float* W_ih    = (const float*)d_in[2];
    const float* W_hh    = (const float*)d_in[3];
    const float* b_ih    = (const float*)d_in[4];
    const float* b_hh    = (const float*)d_in[5];
    const float* W_last  = (const float*)d_in[6];
    const float* b_last  = (const float*)d_in[7];
    float* out = (float*)d_out;
    char* wsb = (char*)d_ws;                        // 64KB bf16 W g,o fragments
    float* wsloss = (float*)((char*)d_ws + 65536);  // 256 block partials

    const int B      = in_sizes[0] / (OBS * 2);   // 32768
    const int blocks = B / 128;                    // 256

    prep_w<<<16, 256, 0, stream>>>(W_hh, wsb);
    lstm_persist<<<blocks, 512, LDS_BYTES, stream>>>(traj_in, traj_gt, W_ih, W_hh,
                                                     b_ih, b_hh, W_last, b_last,
                                                     out, wsb, wsloss);
    loss_reduce<<<1, 256, 0, stream>>>(wsloss, out, blocks, out_size - 1);
}

// Round 5
// 198.395 us; speedup vs baseline: 2.2729x; 2.2564x over previous
//
#include <hip/hip_runtime.h>

#define OBS 8
#define PREDL 12
#define NSTEP 19   // 8 obs + 11 pred-advance steps

// LDS map (bytes)
#define W_OFF     0        // 131072: W_hh all 4 gates, 512 rows x 256B bf16, swizzled
#define H_OFF     131072   // 16384: h single buffer, 64 rows x 256B, swizzled
#define SCR_OFF   147456   // 4096: head partials [parity][wc][64 rows][2] f32
#define RED_OFF   151552   // 64: loss partials
#define LDS_BYTES 151616

typedef short short8 __attribute__((ext_vector_type(8)));
typedef float f32x16 __attribute__((ext_vector_type(16)));
struct U128 { unsigned a, b, c, d; };

__device__ __forceinline__ float sigm(float x) {
    return __builtin_amdgcn_rcpf(1.0f + __builtin_amdgcn_exp2f(x * -1.4426950408889634f));
}
__device__ __forceinline__ float tanh_(float x) {
    return __builtin_amdgcn_rcpf(1.0f + __builtin_amdgcn_exp2f(x * -2.8853900817779268f)) * 2.0f - 1.0f;
}
__device__ __forceinline__ unsigned f2bf(float f) {
    unsigned u = __builtin_bit_cast(unsigned, f);
    u += 0x7fffu + ((u >> 16) & 1u);   // RNE
    return u >> 16;
}
#define DPP_ADD(v, ctrl) \
    v += __builtin_bit_cast(float, __builtin_amdgcn_update_dpp(0, __builtin_bit_cast(int, v), ctrl, 0xf, 0xf, true))

__global__ __launch_bounds__(512)
void lstm_persist(const float* __restrict__ traj_in, const float* __restrict__ traj_gt,
                  const float* __restrict__ W_ih, const float* __restrict__ W_hh,
                  const float* __restrict__ b_ih, const float* __restrict__ b_hh,
                  const float* __restrict__ W_last, const float* __restrict__ b_last,
                  float* __restrict__ out, float* __restrict__ wsloss)
{
    extern __shared__ char smem[];
    const int tid  = threadIdx.x;
    const int lane = tid & 63;
    const int wave = tid >> 6;
    const int l31  = lane & 31;
    const int half = lane >> 5;
    const int sw   = (lane & 7) << 4;
    const int wm   = wave >> 2;        // M-group: rows wm*32..+31
    const int wc   = wave & 3;         // col group: gate cols wc*32..+31
    const int col0 = wc * 32;
    const int b0   = blockIdx.x * 64;
    const int myrow = wm * 32 + l31;   // block-local batch row (A/x/emit)

    // ---- stage ALL of W_hh (512 rows f32[128]) -> LDS bf16, 256B rows, swizzled
    for (int it = 0; it < 32; ++it) {
        int i = it * 512 + tid;           // 16384 float4 items
        int n = i >> 5, q = i & 31;       // row, float4-within-row
        const float4 w = *(const float4*)(W_hh + (size_t)n * 128 + q * 4);
        uint2 pk = { f2bf(w.x) | (f2bf(w.y) << 16), f2bf(w.z) | (f2bf(w.w) << 16) };
        *(uint2*)(smem + W_OFF + n * 256 + ((q * 8) ^ ((n & 7) << 4))) = pk;
    }
    // ---- zero h buffer
    for (int i = 0; i < 8; ++i)
        *(unsigned*)(smem + H_OFF + (tid + i * 512) * 4) = 0u;

    // ---- K-extension B-fragments (x-weights + bias), step-invariant, 16 VGPRs
    short8 Ee[4];
    #pragma unroll
    for (int gg = 0; gg < 4; ++gg) {
        U128 q = { 0u, 0u, 0u, 0u };
        if (half == 0) {
            int n = gg * 128 + col0 + l31;
            float2 wi = *(const float2*)(W_ih + n * 2);
            float bsum = b_ih[n] + b_hh[n];
            q.a = f2bf(wi.x) | (f2bf(wi.y) << 16);
            q.b = f2bf(bsum);
        }
        Ee[gg] = __builtin_bit_cast(short8, q);
    }

    const float wl0 = W_last[col0 + l31];
    const float wl1 = W_last[128 + col0 + l31];
    const float bl0 = b_last[0], bl1 = b_last[1];

    __syncthreads();

    float c_[16];
    #pragma unroll
    for (int r = 0; r < 16; ++r) c_[r] = 0.f;
    float lossAcc = 0.f;
    unsigned xv = 0u;   // packed bf16 (x0,x1), valid at half==0

    for (int t = 0; t < NSTEP; ++t) {
        // ---- acquire x for this step
        if (t < OBS) {
            if (half == 0) {
                float2 xa = *(const float2*)(traj_in + ((size_t)(b0 + myrow) * OBS + t) * 2);
                xv = f2bf(xa.x) | (f2bf(xa.y) << 16);
            }
        } else {
            const int sp = (t - 1) & 1;
            if (half == 0) {
                const char* base = smem + SCR_OFF + sp * 2048 + myrow * 8;
                float2 s0 = *(const float2*)(base);
                float2 s1 = *(const float2*)(base + 512);
                float2 s2 = *(const float2*)(base + 1024);
                float2 s3 = *(const float2*)(base + 1536);
                float o0 = ((s0.x + s1.x) + (s2.x + s3.x)) + bl0;
                float o1 = ((s0.y + s1.y) + (s2.y + s3.y)) + bl1;
                xv = f2bf(o0) | (f2bf(o1) << 16);
                if (wc == 0) {                 // emit prediction p = t-8
                    int p = t - OBS;
                    size_t og = ((size_t)(b0 + myrow) * PREDL + p) * 2;
                    float2 gt = *(const float2*)(traj_gt + og);
                    *(float2*)(out + og) = make_float2(o0, o1);
                    float d0 = o0 - gt.x, d1 = o1 - gt.y;
                    lossAcc = fmaf(d0, d0, fmaf(d1, d1, lossAcc));
                }
            }
        }

        // ---- A fragments from h (read before overwrite)
        short8 a[8];
        #pragma unroll
        for (int ks = 0; ks < 8; ++ks)
            a[ks] = *(const short8*)(smem + H_OFF + myrow * 256 + ((ks * 32 + half * 16) ^ sw));

        __syncthreads();   // all reads of h done before this step's writes

        // ---- 4-gate MFMA accumulate (all B from LDS)
        f32x16 ac0{}, ac1{}, ac2{}, ac3{};
        #pragma unroll
        for (int ks = 0; ks < 8; ++ks) {
            const int bb = (ks * 32 + half * 16) ^ sw;
            const char* wb = smem + W_OFF + (col0 + l31) * 256 + bb;
            short8 bi  = *(const short8*)(wb);
            short8 bf_ = *(const short8*)(wb + 128 * 256);
            short8 bg  = *(const short8*)(wb + 256 * 256);
            short8 bo  = *(const short8*)(wb + 384 * 256);
            ac0 = __builtin_amdgcn_mfma_f32_32x32x16_bf16(a[ks], bi,  ac0, 0, 0, 0);
            ac1 = __builtin_amdgcn_mfma_f32_32x32x16_bf16(a[ks], bf_, ac1, 0, 0, 0);
            ac2 = __builtin_amdgcn_mfma_f32_32x32x16_bf16(a[ks], bg,  ac2, 0, 0, 0);
            ac3 = __builtin_amdgcn_mfma_f32_32x32x16_bf16(a[ks], bo,  ac3, 0, 0, 0);
        }
        {   // K-extension slice: x * W_ih^T + bias
            U128 ax = { (half == 0) ? xv : 0u,
                        (half == 0) ? 0x00003F80u : 0u, 0u, 0u };   // [x0,x1],[1.0,0]
            short8 aext = __builtin_bit_cast(short8, ax);
            ac0 = __builtin_amdgcn_mfma_f32_32x32x16_bf16(aext, Ee[0], ac0, 0, 0, 0);
            ac1 = __builtin_amdgcn_mfma_f32_32x32x16_bf16(aext, Ee[1], ac1, 0, 0, 0);
            ac2 = __builtin_amdgcn_mfma_f32_32x32x16_bf16(aext, Ee[2], ac2, 0, 0, 0);
            ac3 = __builtin_amdgcn_mfma_f32_32x32x16_bf16(aext, Ee[3], ac3, 0, 0, 0);
        }

        // ---- elementwise + h write + head partials
        const bool doHead = (t >= OBS - 1);
        #pragma unroll
        for (int r = 0; r < 16; ++r) {
            float iv = sigm(ac0[r]);
            float fv = sigm(ac1[r]);
            float gv = tanh_(ac2[r]);
            float ov = sigm(ac3[r]);
            float cv = fmaf(fv, c_[r], iv * gv);
            c_[r] = cv;
            float hv = ov * tanh_(cv);
            const int rrow = (r & 3) + 8 * (r >> 2) + 4 * half;
            const int arow = wm * 32 + rrow;
            unsigned ubf = f2bf(hv);
            unsigned nb  = (unsigned)__builtin_amdgcn_update_dpp(0, (int)ubf, 0xB1, 0xf, 0xf, true);
            if (!(l31 & 1))
                *(unsigned*)(smem + H_OFF + arow * 256 +
                             (((col0 + l31) * 2) ^ ((rrow & 7) << 4))) = ubf | (nb << 16);
            if (doHead) {
                float rl = fmaxf(hv, 0.f);
                float v0 = rl * wl0, v1 = rl * wl1;
                DPP_ADD(v0, 0x111); DPP_ADD(v0, 0x112); DPP_ADD(v0, 0x114);
                DPP_ADD(v0, 0x118); DPP_ADD(v0, 0x142);
                DPP_ADD(v1, 0x111); DPP_ADD(v1, 0x112); DPP_ADD(v1, 0x114);
                DPP_ADD(v1, 0x118); DPP_ADD(v1, 0x142);
                if (l31 == 31)
                    *(float2*)(smem + SCR_OFF + (t & 1) * 2048 + wc * 512 + arow * 8) =
                        make_float2(v0, v1);
            }
        }
        __syncthreads();
    }

    // ---- tail: emit p = 11 from head(18) partials (parity 18&1 == 0)
    if (half == 0 && wc == 0) {
        const char* base = smem + SCR_OFF + myrow * 8;
        float2 s0 = *(const float2*)(base);
        float2 s1 = *(const float2*)(base + 512);
        float2 s2 = *(const float2*)(base + 1024);
        float2 s3 = *(const float2*)(base + 1536);
        float o0 = ((s0.x + s1.x) + (s2.x + s3.x)) + bl0;
        float o1 = ((s0.y + s1.y) + (s2.y + s3.y)) + bl1;
        size_t og = ((size_t)(b0 + myrow) * PREDL + (PREDL - 1)) * 2;
        float2 gt = *(const float2*)(traj_gt + og);
        *(float2*)(out + og) = make_float2(o0, o1);
        float d0 = o0 - gt.x, d1 = o1 - gt.y;
        lossAcc = fmaf(d0, d0, fmaf(d1, d1, lossAcc));
    }

    // ---- block loss partial (deterministic)
    #pragma unroll
    for (int s = 1; s < 64; s <<= 1) lossAcc += __shfl_xor(lossAcc, s, 64);
    float* sred = (float*)(smem + RED_OFF);
    if (lane == 0) sred[wave] = lossAcc;
    __syncthreads();
    if (tid == 0) {
        float s = 0.f;
        #pragma unroll
        for (int i = 0; i < 8; ++i) s += sred[i];
        wsloss[blockIdx.x] = s;
    }
}

__global__ void loss_reduce(const float* __restrict__ wsloss, float* __restrict__ out,
                            int nblk, int nelem)
{
    __shared__ float sacc[8];
    int tid = threadIdx.x;   // 512
    float v = (tid < nblk) ? wsloss[tid] : 0.f;
    #pragma unroll
    for (int s = 1; s < 64; s <<= 1) v += __shfl_xor(v, s, 64);
    if ((tid & 63) == 0) sacc[tid >> 6] = v;
    __syncthreads();
    if (tid == 0) {
        float s = 0.f;
        #pragma unroll
        for (int i = 0; i < 8; ++i) s += sacc[i];
        out[nelem] = s / (float)nelem;
    }
}

extern "C" void kernel_launch(void* const* d_in, const int* in_sizes, int n_in,
                              void* d_out, int out_size, void* d_ws, size_t ws_size,
                              hipStream_t stream)
{
    const float* traj_in = (const float*)d_in[0];
    const float* traj_gt = (const float*)d_in[1];
    const float* W_ih    = (const float*)d_in[2];
    const float* W_hh    = (const float*)d_in[3];
    const float* b_ih    = (const float*)d_in[4];
    const float* b_hh    = (const float*)d_in[5];
    const float* W_last  = (const float*)d_in[6];
    const float* b_last  = (const float*)d_in[7];
    float* out = (float*)d_out;
    float* wsloss = (float*)d_ws;

    const int B      = in_sizes[0] / (OBS * 2);   // 32768
    const int blocks = B / 64;                     // 512

    lstm_persist<<<blocks, 512, LDS_BYTES, stream>>>(traj_in, traj_gt, W_ih, W_hh,
                                                     b_ih, b_hh, W_last, b_last,
                                                     out, wsloss);
    loss_reduce<<<1, 512, 0, stream>>>(wsloss, out, blocks, out_size - 1);
}